// Round 1
// baseline (304.484 us; speedup 1.0000x reference)
//
#include <hip/hip_runtime.h>
#include <math.h>

#define B_ 16
#define S_ 8192
#define H_ 256

#define S_TILE 64
#define NCHUNK 256
#define CHUNK_S (S_ / NCHUNK)  // 32

// ---------------------------------------------------------------------------
// prep: blocks 0..255 transpose W2 -> W2T (W2T[h][k] = W2[k][h]);
//       blocks 256..271 compute h1[b][k] = sum_h hidden[b][h]*W1[k][h]
// ---------------------------------------------------------------------------
__global__ __launch_bounds__(256) void prep_kernel(
    const float* __restrict__ hidden, const float* __restrict__ W1,
    const float* __restrict__ W2, float* __restrict__ W2T,
    float* __restrict__ h1) {
  int blk = blockIdx.x;
  int t = threadIdx.x;
  if (blk < H_) {
    // write coalesced over k=t
    W2T[blk * H_ + t] = W2[t * H_ + blk];
  } else {
    int b = blk - H_;
    const float* hrow = hidden + b * H_;
    const float* wrow = W1 + t * H_;
    float acc = 0.f;
#pragma unroll 8
    for (int h = 0; h < H_; ++h) acc += hrow[h] * wrow[h];
    h1[b * H_ + t] = acc;
  }
}

// ---------------------------------------------------------------------------
// scores: one block per (b, 64-s tile). enc tile staged in LDS (64 KiB).
// Thread (ts=tid>>5, tk=tid&31) owns 8 s-rows (ts*8+i) x 8 k-cols (tk*8+j).
// h2[s][k] = sum_h enc[s][h] * W2T[h][k]; then score = sum_k tanh(h2+h1)*V[k]
// reduced across the 32 tk-lanes with width-32 shfl_xor.
// ---------------------------------------------------------------------------
__global__ __launch_bounds__(256, 2) void scores_kernel(
    const float* __restrict__ enc, const float* __restrict__ W2T,
    const float* __restrict__ h1, const float* __restrict__ V,
    float* __restrict__ scores) {
  __shared__ float enc_lds[S_TILE * H_];  // 64 KiB

  const int b = blockIdx.y;
  const int s0 = blockIdx.x * S_TILE;
  const int tid = threadIdx.x;

  // stage enc tile: 64 rows x 256 floats = 4096 float4
  const float4* src = (const float4*)(enc + ((size_t)(b * S_ + s0)) * H_);
  float4* dst = (float4*)enc_lds;
#pragma unroll
  for (int i = 0; i < (S_TILE * H_ / 4) / 256; ++i)
    dst[tid + i * 256] = src[tid + i * 256];
  __syncthreads();

  const int ts = tid >> 5;
  const int tk = tid & 31;
  const int k0 = tk * 8;

  float acc[8][8];
#pragma unroll
  for (int i = 0; i < 8; ++i)
#pragma unroll
    for (int j = 0; j < 8; ++j) acc[i][j] = 0.f;

  const float4* enc4 = (const float4*)enc_lds;

#pragma unroll 2
  for (int h4 = 0; h4 < H_ / 4; ++h4) {
    float4 w0[4], w1[4];
#pragma unroll
    for (int r = 0; r < 4; ++r) {
      const float4* wp = (const float4*)(W2T + (h4 * 4 + r) * H_ + k0);
      w0[r] = wp[0];
      w1[r] = wp[1];
    }
#pragma unroll
    for (int i = 0; i < 8; ++i) {
      float4 e = enc4[(ts * 8 + i) * (H_ / 4) + h4];
      float ev[4] = {e.x, e.y, e.z, e.w};
#pragma unroll
      for (int r = 0; r < 4; ++r) {
        acc[i][0] += ev[r] * w0[r].x;
        acc[i][1] += ev[r] * w0[r].y;
        acc[i][2] += ev[r] * w0[r].z;
        acc[i][3] += ev[r] * w0[r].w;
        acc[i][4] += ev[r] * w1[r].x;
        acc[i][5] += ev[r] * w1[r].y;
        acc[i][6] += ev[r] * w1[r].z;
        acc[i][7] += ev[r] * w1[r].w;
      }
    }
  }

  // epilogue: tanh + V-dot + cross-lane reduce
  float h1v[8], Vv[8];
#pragma unroll
  for (int j = 0; j < 8; ++j) {
    h1v[j] = h1[b * H_ + k0 + j];
    Vv[j] = V[k0 + j];
  }
#pragma unroll
  for (int i = 0; i < 8; ++i) {
    float sum = 0.f;
#pragma unroll
    for (int j = 0; j < 8; ++j) sum += tanhf(acc[i][j] + h1v[j]) * Vv[j];
#pragma unroll
    for (int off = 16; off > 0; off >>= 1) sum += __shfl_xor(sum, off, 32);
    if (tk == 0) scores[b * S_ + s0 + ts * 8 + i] = sum;
  }
}

// ---------------------------------------------------------------------------
// softmax over S per batch row. grid=B, block=1024, 8 values/thread in regs.
// ---------------------------------------------------------------------------
__global__ __launch_bounds__(1024) void softmax_kernel(
    const float* __restrict__ scores, float* __restrict__ attn) {
  __shared__ float redm[17];
  __shared__ float reds[17];
  const int b = blockIdx.x;
  const int tid = threadIdx.x;
  const int wave = tid >> 6;
  const int lane = tid & 63;

  const float4* sp = (const float4*)(scores + b * S_);
  float4 v0 = sp[tid * 2];
  float4 v1 = sp[tid * 2 + 1];
  float x[8] = {v0.x, v0.y, v0.z, v0.w, v1.x, v1.y, v1.z, v1.w};

  float m = x[0];
#pragma unroll
  for (int j = 1; j < 8; ++j) m = fmaxf(m, x[j]);
#pragma unroll
  for (int off = 32; off > 0; off >>= 1) m = fmaxf(m, __shfl_xor(m, off, 64));
  if (lane == 0) redm[wave] = m;
  __syncthreads();
  if (tid == 0) {
    float mm = redm[0];
    for (int i = 1; i < 16; ++i) mm = fmaxf(mm, redm[i]);
    redm[16] = mm;
  }
  __syncthreads();
  m = redm[16];

  float e[8];
  float s = 0.f;
#pragma unroll
  for (int j = 0; j < 8; ++j) {
    e[j] = expf(x[j] - m);
    s += e[j];
  }
#pragma unroll
  for (int off = 32; off > 0; off >>= 1) s += __shfl_xor(s, off, 64);
  if (lane == 0) reds[wave] = s;
  __syncthreads();
  if (tid == 0) {
    float ss = 0.f;
    for (int i = 0; i < 16; ++i) ss += reds[i];
    reds[16] = ss;
  }
  __syncthreads();
  const float inv = 1.f / reds[16];

  float4 o0 = {e[0] * inv, e[1] * inv, e[2] * inv, e[3] * inv};
  float4 o1 = {e[4] * inv, e[5] * inv, e[6] * inv, e[7] * inv};
  float4* op = (float4*)(attn + b * S_);
  op[tid * 2] = o0;
  op[tid * 2 + 1] = o1;
}

// ---------------------------------------------------------------------------
// context partial sums: block (chunk, b), thread = h. 32 s-rows per chunk.
// ---------------------------------------------------------------------------
__global__ __launch_bounds__(256) void ctx_partial_kernel(
    const float* __restrict__ enc, const float* __restrict__ attn,
    float* __restrict__ partial) {
  const int chunk = blockIdx.x;
  const int b = blockIdx.y;
  const int h = threadIdx.x;
  const int sbase = chunk * CHUNK_S;
  const float* ap = attn + b * S_ + sbase;
  const float* ep = enc + ((size_t)(b * S_ + sbase)) * H_ + h;
  float acc = 0.f;
#pragma unroll 8
  for (int s = 0; s < CHUNK_S; ++s) acc += ap[s] * ep[(size_t)s * H_];
  partial[(b * NCHUNK + chunk) * H_ + h] = acc;
}

// ---------------------------------------------------------------------------
// reduce partials -> context (ws) + out1. grid=B, block=256 (thread = h).
// ---------------------------------------------------------------------------
__global__ __launch_bounds__(256) void ctx_reduce_kernel(
    const float* __restrict__ partial, float* __restrict__ context,
    float* __restrict__ out1) {
  const int b = blockIdx.x;
  const int h = threadIdx.x;
  float acc = 0.f;
#pragma unroll 4
  for (int c = 0; c < NCHUNK; ++c) acc += partial[(b * NCHUNK + c) * H_ + h];
  context[b * H_ + h] = acc;
  out1[b * H_ + h] = acc;
}

// ---------------------------------------------------------------------------
// broadcast context over S: out0[b][h][s] = context[b][h]. grid = B*H.
// ---------------------------------------------------------------------------
__global__ __launch_bounds__(256) void tile_kernel(
    const float* __restrict__ context, float* __restrict__ out0) {
  const int bh = blockIdx.x;
  const float v = context[bh];
  float4 vv = {v, v, v, v};
  float4* op = (float4*)(out0 + (size_t)bh * S_);
#pragma unroll 4
  for (int i = threadIdx.x; i < S_ / 4; i += 256) op[i] = vv;
}

extern "C" void kernel_launch(void* const* d_in, const int* in_sizes, int n_in,
                              void* d_out, int out_size, void* d_ws,
                              size_t ws_size, hipStream_t stream) {
  const float* hidden = (const float*)d_in[0];
  const float* enc = (const float*)d_in[1];
  const float* W1 = (const float*)d_in[2];
  const float* W2 = (const float*)d_in[3];
  const float* V = (const float*)d_in[4];

  float* out0 = (float*)d_out;                    // [B,H,S] context tiled
  float* out1 = out0 + (size_t)B_ * H_ * S_;      // [B,H]   context
  float* out2 = out1 + B_ * H_;                   // [B,S]   attn

  float* ws = (float*)d_ws;
  float* W2T = ws;                                // 65536
  float* h1 = W2T + H_ * H_;                      // 4096
  float* scores = h1 + B_ * H_;                   // 131072
  float* partial = scores + B_ * S_;              // B*NCHUNK*H = 1048576
  float* context = partial + B_ * NCHUNK * H_;    // 4096

  prep_kernel<<<H_ + B_, 256, 0, stream>>>(hidden, W1, W2, W2T, h1);
  scores_kernel<<<dim3(S_ / S_TILE, B_), 256, 0, stream>>>(enc, W2T, h1, V,
                                                           scores);
  softmax_kernel<<<B_, 1024, 0, stream>>>(scores, out2);
  ctx_partial_kernel<<<dim3(NCHUNK, B_), 256, 0, stream>>>(enc, out2, partial);
  ctx_reduce_kernel<<<B_, 256, 0, stream>>>(partial, context, out1);
  tile_kernel<<<B_ * H_, 256, 0, stream>>>(context, out0);
}

// Round 2
// 164.806 us; speedup vs baseline: 1.8475x; 1.8475x over previous
//
#include <hip/hip_runtime.h>
#include <hip/hip_bf16.h>
#include <math.h>

#define B_ 16
#define S_ 8192
#define H_ 256
#define NCHUNK 256
#define CHUNK_S (S_ / NCHUNK)  // 32

using bf16x8 = __attribute__((ext_vector_type(8))) short;
using f32x4 = __attribute__((ext_vector_type(4))) float;

// fp32 -> bf16 with round-to-nearest-even (no NaN handling; inputs are finite)
__device__ inline short f2bf(float x) {
  union {
    float f;
    unsigned u;
  } v;
  v.f = x;
  unsigned r = v.u + 0x7FFFu + ((v.u >> 16) & 1u);
  return (short)(r >> 16);
}

// tanh(x) = 1 - 2/(exp2(x*2*log2e)+1); hw exp2 + rcp, ~1e-6 rel err
__device__ inline float fast_tanh(float x) {
  float e = exp2f(x * 2.885390082f);
  return fmaf(-2.f, __builtin_amdgcn_rcpf(e + 1.f), 1.f);
}

// ---------------------------------------------------------------------------
// prep: blocks 0..31 pack W2 into MFMA B-fragment-major bf16:
//   W2f[((ks*16 + j0)*64 + l)*8 + t] = bf16(W2[j0*16 + (l&15)][ks*32 + (l>>4)*8 + t])
// blocks 32..47: h1[b][k] = sum_h hidden[b][h]*W1[k][h]  (fp32, exact path)
// ---------------------------------------------------------------------------
__global__ __launch_bounds__(256) void prep_kernel(
    const float* __restrict__ hidden, const float* __restrict__ W1,
    const float* __restrict__ W2, short* __restrict__ W2f,
    float* __restrict__ h1) {
  const int blk = blockIdx.x;
  const int t = threadIdx.x;
  if (blk < 32) {
    const int gid = blk * 256 + t;  // 0..8191
    const int l = gid & 63;
    const int j0 = (gid >> 6) & 15;
    const int ks = gid >> 10;  // 0..7
    const int row = j0 * 16 + (l & 15);
    const int col = ks * 32 + (l >> 4) * 8;
    const float* wp = W2 + row * H_ + col;
    bf16x8 out;
#pragma unroll
    for (int i = 0; i < 8; ++i) out[i] = f2bf(wp[i]);
    *(bf16x8*)(W2f + (size_t)gid * 8) = out;
  } else {
    const int b = blk - 32;
    const float* hrow = hidden + b * H_;
    const float* wrow = W1 + t * H_;
    float acc = 0.f;
#pragma unroll 8
    for (int h = 0; h < H_; ++h) acc += hrow[h] * wrow[h];
    h1[b * H_ + t] = acc;
  }
}

// ---------------------------------------------------------------------------
// scores: one wave per 32 s-rows. mfma_f32_16x16x32_bf16.
//   A: enc rows (fp32->bf16 in reg), lane l holds row (l&15), k=(l>>4)*8..+7
//   B: packed W2f fragments, 16B/lane coalesced
//   C/D: col=lane&15, row=(lane>>4)*4+reg  [verified m89/m91]
// Epilogue: score[s] = sum_j fast_tanh(h2[s][j] + h1[b][j]) * V[j],
// reduced across the 16 lanes of each (lane>>4) group.
// ---------------------------------------------------------------------------
__global__ __launch_bounds__(256, 2) void scores_kernel(
    const float* __restrict__ enc, const short* __restrict__ W2f,
    const float* __restrict__ h1, const float* __restrict__ V,
    float* __restrict__ scores) {
  const int wave = threadIdx.x >> 6;
  const int l = threadIdx.x & 63;
  const int lo = l & 15;
  const int hi = l >> 4;
  const int job = blockIdx.x * 4 + wave;
  const int b = job >> 8;           // 256 jobs per batch row
  const int s0 = (job & 255) * 32;  // 32 s-rows per wave

  const float* a0 = enc + ((size_t)b * S_ + s0 + lo) * H_ + hi * 8;
  const float* a1 = a0 + 16 * H_;
  const bf16x8* bbase = (const bf16x8*)W2f;

  f32x4 acc[2][16];
#pragma unroll
  for (int m = 0; m < 2; ++m)
#pragma unroll
    for (int j = 0; j < 16; ++j) acc[m][j] = (f32x4){0.f, 0.f, 0.f, 0.f};

#pragma unroll
  for (int ks = 0; ks < 8; ++ks) {
    bf16x8 af0, af1;
    {
      const float4* p0 = (const float4*)(a0 + ks * 32);
      float4 x0 = p0[0];
      float4 x1 = p0[1];
      af0[0] = f2bf(x0.x); af0[1] = f2bf(x0.y);
      af0[2] = f2bf(x0.z); af0[3] = f2bf(x0.w);
      af0[4] = f2bf(x1.x); af0[5] = f2bf(x1.y);
      af0[6] = f2bf(x1.z); af0[7] = f2bf(x1.w);
      const float4* p1 = (const float4*)(a1 + ks * 32);
      float4 y0 = p1[0];
      float4 y1 = p1[1];
      af1[0] = f2bf(y0.x); af1[1] = f2bf(y0.y);
      af1[2] = f2bf(y0.z); af1[3] = f2bf(y0.w);
      af1[4] = f2bf(y1.x); af1[5] = f2bf(y1.y);
      af1[6] = f2bf(y1.z); af1[7] = f2bf(y1.w);
    }
#pragma unroll
    for (int j0 = 0; j0 < 16; ++j0) {
      bf16x8 bf = bbase[(ks * 16 + j0) * 64 + l];
      acc[0][j0] = __builtin_amdgcn_mfma_f32_16x16x32_bf16(af0, bf, acc[0][j0], 0, 0, 0);
      acc[1][j0] = __builtin_amdgcn_mfma_f32_16x16x32_bf16(af1, bf, acc[1][j0], 0, 0, 0);
    }
  }

  // epilogue
  float h1v[16], Vv[16];
  const float* h1p = h1 + b * H_ + lo;
#pragma unroll
  for (int j0 = 0; j0 < 16; ++j0) {
    h1v[j0] = h1p[j0 * 16];
    Vv[j0] = V[j0 * 16 + lo];
  }
  float* sp = scores + b * S_ + s0;
#pragma unroll
  for (int m = 0; m < 2; ++m) {
#pragma unroll
    for (int r = 0; r < 4; ++r) {
      float sum = 0.f;
#pragma unroll
      for (int j0 = 0; j0 < 16; ++j0)
        sum += fast_tanh(acc[m][j0][r] + h1v[j0]) * Vv[j0];
#pragma unroll
      for (int off = 8; off > 0; off >>= 1) sum += __shfl_xor(sum, off, 16);
      if (lo == 0) sp[m * 16 + hi * 4 + r] = sum;
    }
  }
}

// ---------------------------------------------------------------------------
// softmax over S per batch row. grid=B, block=1024, 8 values/thread in regs.
// ---------------------------------------------------------------------------
__global__ __launch_bounds__(1024) void softmax_kernel(
    const float* __restrict__ scores, float* __restrict__ attn) {
  __shared__ float redm[17];
  __shared__ float reds[17];
  const int b = blockIdx.x;
  const int tid = threadIdx.x;
  const int wave = tid >> 6;
  const int lane = tid & 63;

  const float4* sp = (const float4*)(scores + b * S_);
  float4 v0 = sp[tid * 2];
  float4 v1 = sp[tid * 2 + 1];
  float x[8] = {v0.x, v0.y, v0.z, v0.w, v1.x, v1.y, v1.z, v1.w};

  float m = x[0];
#pragma unroll
  for (int j = 1; j < 8; ++j) m = fmaxf(m, x[j]);
#pragma unroll
  for (int off = 32; off > 0; off >>= 1) m = fmaxf(m, __shfl_xor(m, off, 64));
  if (lane == 0) redm[wave] = m;
  __syncthreads();
  if (tid == 0) {
    float mm = redm[0];
    for (int i = 1; i < 16; ++i) mm = fmaxf(mm, redm[i]);
    redm[16] = mm;
  }
  __syncthreads();
  m = redm[16];

  float e[8];
  float s = 0.f;
#pragma unroll
  for (int j = 0; j < 8; ++j) {
    e[j] = expf(x[j] - m);
    s += e[j];
  }
#pragma unroll
  for (int off = 32; off > 0; off >>= 1) s += __shfl_xor(s, off, 64);
  if (lane == 0) reds[wave] = s;
  __syncthreads();
  if (tid == 0) {
    float ss = 0.f;
    for (int i = 0; i < 16; ++i) ss += reds[i];
    reds[16] = ss;
  }
  __syncthreads();
  const float inv = 1.f / reds[16];

  float4 o0 = {e[0] * inv, e[1] * inv, e[2] * inv, e[3] * inv};
  float4 o1 = {e[4] * inv, e[5] * inv, e[6] * inv, e[7] * inv};
  float4* op = (float4*)(attn + b * S_);
  op[tid * 2] = o0;
  op[tid * 2 + 1] = o1;
}

// ---------------------------------------------------------------------------
// context partial sums: block (chunk, b), thread = h. 32 s-rows per chunk.
// ---------------------------------------------------------------------------
__global__ __launch_bounds__(256) void ctx_partial_kernel(
    const float* __restrict__ enc, const float* __restrict__ attn,
    float* __restrict__ partial) {
  const int chunk = blockIdx.x;
  const int b = blockIdx.y;
  const int h = threadIdx.x;
  const int sbase = chunk * CHUNK_S;
  const float* ap = attn + b * S_ + sbase;
  const float* ep = enc + ((size_t)(b * S_ + sbase)) * H_ + h;
  float acc = 0.f;
#pragma unroll 8
  for (int s = 0; s < CHUNK_S; ++s) acc += ap[s] * ep[(size_t)s * H_];
  partial[(b * NCHUNK + chunk) * H_ + h] = acc;
}

// ---------------------------------------------------------------------------
// reduce partials -> out1 (context). grid=B, block=256 (thread = h).
// ---------------------------------------------------------------------------
__global__ __launch_bounds__(256) void ctx_reduce_kernel(
    const float* __restrict__ partial, float* __restrict__ out1) {
  const int b = blockIdx.x;
  const int h = threadIdx.x;
  float acc = 0.f;
#pragma unroll 4
  for (int c = 0; c < NCHUNK; ++c) acc += partial[(b * NCHUNK + c) * H_ + h];
  out1[b * H_ + h] = acc;
}

// ---------------------------------------------------------------------------
// broadcast context over S: out0[b][h][s] = context[b][h]. grid = B*H.
// ---------------------------------------------------------------------------
__global__ __launch_bounds__(256) void tile_kernel(
    const float* __restrict__ context, float* __restrict__ out0) {
  const int bh = blockIdx.x;
  const float v = context[bh];
  float4 vv = {v, v, v, v};
  float4* op = (float4*)(out0 + (size_t)bh * S_);
#pragma unroll 4
  for (int i = threadIdx.x; i < S_ / 4; i += 256) op[i] = vv;
}

extern "C" void kernel_launch(void* const* d_in, const int* in_sizes, int n_in,
                              void* d_out, int out_size, void* d_ws,
                              size_t ws_size, hipStream_t stream) {
  const float* hidden = (const float*)d_in[0];
  const float* enc = (const float*)d_in[1];
  const float* W1 = (const float*)d_in[2];
  const float* W2 = (const float*)d_in[3];
  const float* V = (const float*)d_in[4];

  float* out0 = (float*)d_out;                // [B,H,S] context tiled
  float* out1 = out0 + (size_t)B_ * H_ * S_;  // [B,H]   context
  float* out2 = out1 + B_ * H_;               // [B,S]   attn

  float* ws = (float*)d_ws;
  short* W2f = (short*)ws;                    // 65536 shorts = 32768 float slots
  float* h1 = ws + 32768;                     // 4096
  float* scores = h1 + B_ * H_;               // 131072
  float* partial = scores + (size_t)B_ * S_;  // B*NCHUNK*H = 1048576

  prep_kernel<<<48, 256, 0, stream>>>(hidden, W1, W2, W2f, h1);
  scores_kernel<<<(B_ * S_ / 32) / 4, 256, 0, stream>>>(enc, W2f, h1, V,
                                                        scores);
  softmax_kernel<<<B_, 1024, 0, stream>>>(scores, out2);
  ctx_partial_kernel<<<dim3(NCHUNK, B_), 256, 0, stream>>>(enc, out2, partial);
  ctx_reduce_kernel<<<B_, 256, 0, stream>>>(partial, out1);
  tile_kernel<<<B_ * H_, 256, 0, stream>>>(out1, out0);
}

// Round 3
// 113.282 us; speedup vs baseline: 2.6878x; 1.4548x over previous
//
#include <hip/hip_runtime.h>
#include <hip/hip_bf16.h>
#include <math.h>

#define B_ 16
#define S_ 8192
#define H_ 256
#define NCHUNK 256
#define CHUNK_S (S_ / NCHUNK)  // 32

#define TILE_R 32    // s-rows per tile
#define T_PER_BLK 8  // tiles per block -> block covers 256 rows
#define LROW 264     // shorts per LDS row: 256 + 8 pad (528 B, 16B-aligned)

using bf16x8 = __attribute__((ext_vector_type(8))) short;
using f32x4 = __attribute__((ext_vector_type(4))) float;

// fp32 -> bf16 round-to-nearest-even
__device__ inline short f2bf(float x) {
  union {
    float f;
    unsigned u;
  } v;
  v.f = x;
  unsigned r = v.u + 0x7FFFu + ((v.u >> 16) & 1u);
  return (short)(r >> 16);
}

__device__ inline bf16x8 pack8(float4 a, float4 b) {
  bf16x8 o;
  o[0] = f2bf(a.x); o[1] = f2bf(a.y); o[2] = f2bf(a.z); o[3] = f2bf(a.w);
  o[4] = f2bf(b.x); o[5] = f2bf(b.y); o[6] = f2bf(b.z); o[7] = f2bf(b.w);
  return o;
}

// tanh(x) = 1 - 2/(exp2(2x*log2e)+1)
__device__ inline float fast_tanh(float x) {
  float e = exp2f(x * 2.885390082f);
  return fmaf(-2.f, __builtin_amdgcn_rcpf(e + 1.f), 1.f);
}

// ---------------------------------------------------------------------------
// prep: blocks 0..31 pack W2 into MFMA B-fragment-major bf16:
//   W2f[((ks*16 + j0)*64 + l)*8 + e] = bf16(W2[j0*16 + (l&15)][ks*32 + (l>>4)*8 + e])
// blocks 32..47: h1[b][k] = sum_h hidden[b][h]*W1[k][h]
// ---------------------------------------------------------------------------
__global__ __launch_bounds__(256) void prep_kernel(
    const float* __restrict__ hidden, const float* __restrict__ W1,
    const float* __restrict__ W2, short* __restrict__ W2f,
    float* __restrict__ h1) {
  const int blk = blockIdx.x;
  const int t = threadIdx.x;
  if (blk < 32) {
    const int gid = blk * 256 + t;  // 0..8191
    const int l = gid & 63;
    const int j0 = (gid >> 6) & 15;
    const int ks = gid >> 10;  // 0..7
    const int row = j0 * 16 + (l & 15);
    const int col = ks * 32 + (l >> 4) * 8;
    const float* wp = W2 + row * H_ + col;
    bf16x8 out;
#pragma unroll
    for (int i = 0; i < 8; ++i) out[i] = f2bf(wp[i]);
    *(bf16x8*)(W2f + (size_t)gid * 8) = out;
  } else {
    const int b = blk - 32;
    const float* hrow = hidden + b * H_;
    const float* wrow = W1 + t * H_;
    float acc = 0.f;
#pragma unroll 8
    for (int h = 0; h < H_; ++h) acc += hrow[h] * wrow[h];
    h1[b * H_ + t] = acc;
  }
}

// ---------------------------------------------------------------------------
// scores: weight-stationary MFMA. 512 threads = 8 waves; wave w owns
// j0 in {2w, 2w+1}, B-frags in regs for the whole block lifetime.
// Block processes T_PER_BLK tiles of 32 s-rows; enc staged fp32->bf16 into
// double-buffered LDS (row-major, +8-short row pad). Tile t+1 global loads
// are issued before tile t's MFMA phase (latency hidden under compute).
// Cross-wave j-reduction through plds.
// ---------------------------------------------------------------------------
__global__ __launch_bounds__(512, 4) void scores_kernel(
    const float* __restrict__ enc, const short* __restrict__ W2f,
    const float* __restrict__ h1, const float* __restrict__ V,
    float* __restrict__ scores) {
  __shared__ __align__(16) short albuf[2][TILE_R * LROW];  // 2 x 16.9 KiB
  __shared__ float plds[8][TILE_R];

  const int tid = threadIdx.x;
  const int w = tid >> 6;
  const int l = tid & 63;
  const int lo = l & 15;
  const int hi = l >> 4;
  const int bid = blockIdx.x;
  const int b = bid >> 5;                      // 32 blocks per batch row
  const int s_base = (bid & 31) * (TILE_R * T_PER_BLK);

  // --- one-time: B fragments into registers (j0 = 2w, 2w+1) ---
  const bf16x8* bbase = (const bf16x8*)W2f;
  bf16x8 bfrag[8][2];
#pragma unroll
  for (int ks = 0; ks < 8; ++ks)
#pragma unroll
    for (int jj = 0; jj < 2; ++jj)
      bfrag[ks][jj] = bbase[(ks * 16 + (2 * w + jj)) * 64 + l];

  float h1v[2], Vv[2];
#pragma unroll
  for (int jj = 0; jj < 2; ++jj) {
    h1v[jj] = h1[b * H_ + (2 * w + jj) * 16 + lo];
    Vv[jj] = V[(2 * w + jj) * 16 + lo];
  }

  // --- staging geometry: thread handles rows r0 and r0+16, 8 cols at kc0*8 ---
  const int r0 = tid >> 5;        // 0..15
  const int kc0 = tid & 31;       // col chunk (8 floats)
  const float4* gsrc = (const float4*)(enc + (size_t)b * S_ * H_);
  // float4 index for (tile t, row r): (s_base + t*32 + r)*64 + kc0*2

  // prologue: stage tile 0
  {
    size_t gi0 = ((size_t)(s_base + r0) * (H_ / 4)) + kc0 * 2;
    size_t gi1 = ((size_t)(s_base + r0 + 16) * (H_ / 4)) + kc0 * 2;
    float4 a0 = gsrc[gi0], a1 = gsrc[gi0 + 1];
    float4 b0 = gsrc[gi1], b1 = gsrc[gi1 + 1];
    *(bf16x8*)&albuf[0][r0 * LROW + kc0 * 8] = pack8(a0, a1);
    *(bf16x8*)&albuf[0][(r0 + 16) * LROW + kc0 * 8] = pack8(b0, b1);
  }
  __syncthreads();

  for (int t = 0; t < T_PER_BLK; ++t) {
    const int cur = t & 1;

    // issue next tile's global loads now (they complete under the MFMAs)
    float4 na0, na1, nb0, nb1;
    if (t + 1 < T_PER_BLK) {
      size_t gi0 = ((size_t)(s_base + (t + 1) * TILE_R + r0) * (H_ / 4)) + kc0 * 2;
      size_t gi1 = ((size_t)(s_base + (t + 1) * TILE_R + r0 + 16) * (H_ / 4)) + kc0 * 2;
      na0 = gsrc[gi0]; na1 = gsrc[gi0 + 1];
      nb0 = gsrc[gi1]; nb1 = gsrc[gi1 + 1];
    }

    // --- MFMA phase: A from LDS, B from regs ---
    f32x4 acc[2][2];
#pragma unroll
    for (int m = 0; m < 2; ++m)
#pragma unroll
      for (int jj = 0; jj < 2; ++jj) acc[m][jj] = (f32x4){0.f, 0.f, 0.f, 0.f};

    const short* abase = &albuf[cur][lo * LROW + hi * 8];
#pragma unroll
    for (int ks = 0; ks < 8; ++ks) {
      bf16x8 a0 = *(const bf16x8*)(abase + ks * 32);
      bf16x8 a1 = *(const bf16x8*)(abase + 16 * LROW + ks * 32);
      acc[0][0] = __builtin_amdgcn_mfma_f32_16x16x32_bf16(a0, bfrag[ks][0], acc[0][0], 0, 0, 0);
      acc[0][1] = __builtin_amdgcn_mfma_f32_16x16x32_bf16(a0, bfrag[ks][1], acc[0][1], 0, 0, 0);
      acc[1][0] = __builtin_amdgcn_mfma_f32_16x16x32_bf16(a1, bfrag[ks][0], acc[1][0], 0, 0, 0);
      acc[1][1] = __builtin_amdgcn_mfma_f32_16x16x32_bf16(a1, bfrag[ks][1], acc[1][1], 0, 0, 0);
    }

    // --- epilogue: tanh + V-dot, reduce over 16 lo-lanes, stash per-wave ---
#pragma unroll
    for (int m = 0; m < 2; ++m)
#pragma unroll
      for (int r = 0; r < 4; ++r) {
        float p = fast_tanh(acc[m][0][r] + h1v[0]) * Vv[0] +
                  fast_tanh(acc[m][1][r] + h1v[1]) * Vv[1];
        p += __shfl_xor(p, 1, 16);
        p += __shfl_xor(p, 2, 16);
        p += __shfl_xor(p, 4, 16);
        p += __shfl_xor(p, 8, 16);
        if (lo == 0) plds[w][m * 16 + hi * 4 + r] = p;
      }
    __syncthreads();

    // combine the 8 wave-partials, write scores for this tile
    if (tid < TILE_R) {
      float s = 0.f;
#pragma unroll
      for (int ww = 0; ww < 8; ++ww) s += plds[ww][tid];
      scores[(size_t)b * S_ + s_base + t * TILE_R + tid] = s;
    }

    // stage next tile into the other buffer
    if (t + 1 < T_PER_BLK) {
      *(bf16x8*)&albuf[cur ^ 1][r0 * LROW + kc0 * 8] = pack8(na0, na1);
      *(bf16x8*)&albuf[cur ^ 1][(r0 + 16) * LROW + kc0 * 8] = pack8(nb0, nb1);
    }
    __syncthreads();
  }
}

// ---------------------------------------------------------------------------
// softmax over S per batch row. grid=B, block=1024, 8 values/thread in regs.
// ---------------------------------------------------------------------------
__global__ __launch_bounds__(1024) void softmax_kernel(
    const float* __restrict__ scores, float* __restrict__ attn) {
  __shared__ float redm[17];
  __shared__ float reds[17];
  const int b = blockIdx.x;
  const int tid = threadIdx.x;
  const int wave = tid >> 6;
  const int lane = tid & 63;

  const float4* sp = (const float4*)(scores + b * S_);
  float4 v0 = sp[tid * 2];
  float4 v1 = sp[tid * 2 + 1];
  float x[8] = {v0.x, v0.y, v0.z, v0.w, v1.x, v1.y, v1.z, v1.w};

  float m = x[0];
#pragma unroll
  for (int j = 1; j < 8; ++j) m = fmaxf(m, x[j]);
#pragma unroll
  for (int off = 32; off > 0; off >>= 1) m = fmaxf(m, __shfl_xor(m, off, 64));
  if (lane == 0) redm[wave] = m;
  __syncthreads();
  if (tid == 0) {
    float mm = redm[0];
    for (int i = 1; i < 16; ++i) mm = fmaxf(mm, redm[i]);
    redm[16] = mm;
  }
  __syncthreads();
  m = redm[16];

  float e[8];
  float s = 0.f;
#pragma unroll
  for (int j = 0; j < 8; ++j) {
    e[j] = expf(x[j] - m);
    s += e[j];
  }
#pragma unroll
  for (int off = 32; off > 0; off >>= 1) s += __shfl_xor(s, off, 64);
  if (lane == 0) reds[wave] = s;
  __syncthreads();
  if (tid == 0) {
    float ss = 0.f;
    for (int i = 0; i < 16; ++i) ss += reds[i];
    reds[16] = ss;
  }
  __syncthreads();
  const float inv = 1.f / reds[16];

  float4 o0 = {e[0] * inv, e[1] * inv, e[2] * inv, e[3] * inv};
  float4 o1 = {e[4] * inv, e[5] * inv, e[6] * inv, e[7] * inv};
  float4* op = (float4*)(attn + b * S_);
  op[tid * 2] = o0;
  op[tid * 2 + 1] = o1;
}

// ---------------------------------------------------------------------------
// context partial sums: block (chunk, b), thread = h. 32 s-rows per chunk.
// ---------------------------------------------------------------------------
__global__ __launch_bounds__(256) void ctx_partial_kernel(
    const float* __restrict__ enc, const float* __restrict__ attn,
    float* __restrict__ partial) {
  const int chunk = blockIdx.x;
  const int b = blockIdx.y;
  const int h = threadIdx.x;
  const int sbase = chunk * CHUNK_S;
  const float* ap = attn + b * S_ + sbase;
  const float* ep = enc + ((size_t)(b * S_ + sbase)) * H_ + h;
  float acc = 0.f;
#pragma unroll 8
  for (int s = 0; s < CHUNK_S; ++s) acc += ap[s] * ep[(size_t)s * H_];
  partial[(b * NCHUNK + chunk) * H_ + h] = acc;
}

// ---------------------------------------------------------------------------
// reduce partials -> out1 (context). grid=B, block=256 (thread = h).
// ---------------------------------------------------------------------------
__global__ __launch_bounds__(256) void ctx_reduce_kernel(
    const float* __restrict__ partial, float* __restrict__ out1) {
  const int b = blockIdx.x;
  const int h = threadIdx.x;
  float acc = 0.f;
#pragma unroll 4
  for (int c = 0; c < NCHUNK; ++c) acc += partial[(b * NCHUNK + c) * H_ + h];
  out1[b * H_ + h] = acc;
}

// ---------------------------------------------------------------------------
// broadcast context over S: out0[b][h][s] = context[b][h]. grid = B*H.
// ---------------------------------------------------------------------------
__global__ __launch_bounds__(256) void tile_kernel(
    const float* __restrict__ context, float* __restrict__ out0) {
  const int bh = blockIdx.x;
  const float v = context[bh];
  float4 vv = {v, v, v, v};
  float4* op = (float4*)(out0 + (size_t)bh * S_);
#pragma unroll 4
  for (int i = threadIdx.x; i < S_ / 4; i += 256) op[i] = vv;
}

extern "C" void kernel_launch(void* const* d_in, const int* in_sizes, int n_in,
                              void* d_out, int out_size, void* d_ws,
                              size_t ws_size, hipStream_t stream) {
  const float* hidden = (const float*)d_in[0];
  const float* enc = (const float*)d_in[1];
  const float* W1 = (const float*)d_in[2];
  const float* W2 = (const float*)d_in[3];
  const float* V = (const float*)d_in[4];

  float* out0 = (float*)d_out;                // [B,H,S] context tiled
  float* out1 = out0 + (size_t)B_ * H_ * S_;  // [B,H]   context
  float* out2 = out1 + B_ * H_;               // [B,S]   attn

  float* ws = (float*)d_ws;
  short* W2f = (short*)ws;                    // 65536 shorts = 32768 float slots
  float* h1 = ws + 32768;                     // 4096
  float* scores = h1 + B_ * H_;               // 131072
  float* partial = scores + (size_t)B_ * S_;  // B*NCHUNK*H = 1048576

  prep_kernel<<<48, 256, 0, stream>>>(hidden, W1, W2, W2f, h1);
  scores_kernel<<<B_ * S_ / (TILE_R * T_PER_BLK), 512, 0, stream>>>(
      enc, W2f, h1, V, scores);
  softmax_kernel<<<B_, 1024, 0, stream>>>(scores, out2);
  ctx_partial_kernel<<<dim3(NCHUNK, B_), 256, 0, stream>>>(enc, out2, partial);
  ctx_reduce_kernel<<<B_, 256, 0, stream>>>(partial, out1);
  tile_kernel<<<B_ * H_, 256, 0, stream>>>(out1, out0);
}

// Round 4
// 98.153 us; speedup vs baseline: 3.1021x; 1.1541x over previous
//
#include <hip/hip_runtime.h>
#include <hip/hip_bf16.h>
#include <math.h>

#define B_ 16
#define S_ 8192
#define H_ 256
#define NCHUNK 256
#define CHUNK_S (S_ / NCHUNK)  // 32

#define TILE_R 32    // s-rows per tile
#define T_PER_BLK 8  // tiles per block -> block covers 256 rows
#define LROW 264     // shorts per LDS row: 256 + 8 pad (528 B, 16B-aligned)

using bf16x8 = __attribute__((ext_vector_type(8))) short;
using f32x4 = __attribute__((ext_vector_type(4))) float;

// fp32 -> bf16 RNE (scalar, for prep one-time packing)
__device__ inline short f2bf(float x) {
  union {
    float f;
    unsigned u;
  } v;
  v.f = x;
  unsigned r = v.u + 0x7FFFu + ((v.u >> 16) & 1u);
  return (short)(r >> 16);
}

// pack 8 fp32 -> 8 bf16 via v_cvt_pk_bf16_f32 (compiler emits cvt_pk, m240)
__device__ inline bf16x8 pack8(float4 a, float4 b) {
  union {
    __hip_bfloat162 h[4];
    bf16x8 v;
  } u;
  u.h[0] = __float22bfloat162_rn(make_float2(a.x, a.y));
  u.h[1] = __float22bfloat162_rn(make_float2(a.z, a.w));
  u.h[2] = __float22bfloat162_rn(make_float2(b.x, b.y));
  u.h[3] = __float22bfloat162_rn(make_float2(b.z, b.w));
  return u.v;
}

// tanh(x) = 1 - 2/(exp2(2x*log2e)+1)
__device__ inline float fast_tanh(float x) {
  float e = exp2f(x * 2.885390082f);
  return fmaf(-2.f, __builtin_amdgcn_rcpf(e + 1.f), 1.f);
}

// ---------------------------------------------------------------------------
// prep: blocks 0..31 pack W2 into MFMA B-fragment-major bf16:
//   W2f[((ks*16 + j0)*64 + l)*8 + e] = bf16(W2[j0*16 + (l&15)][ks*32 + (l>>4)*8 + e])
// blocks 32..47: h1[b][k] = sum_h hidden[b][h]*W1[k][h]
// ---------------------------------------------------------------------------
__global__ __launch_bounds__(256) void prep_kernel(
    const float* __restrict__ hidden, const float* __restrict__ W1,
    const float* __restrict__ W2, short* __restrict__ W2f,
    float* __restrict__ h1) {
  const int blk = blockIdx.x;
  const int t = threadIdx.x;
  if (blk < 32) {
    const int gid = blk * 256 + t;  // 0..8191
    const int l = gid & 63;
    const int j0 = (gid >> 6) & 15;
    const int ks = gid >> 10;  // 0..7
    const int row = j0 * 16 + (l & 15);
    const int col = ks * 32 + (l >> 4) * 8;
    const float* wp = W2 + row * H_ + col;
    bf16x8 out;
#pragma unroll
    for (int i = 0; i < 8; ++i) out[i] = f2bf(wp[i]);
    *(bf16x8*)(W2f + (size_t)gid * 8) = out;
  } else {
    const int b = blk - 32;
    const float* hrow = hidden + b * H_;
    const float* wrow = W1 + t * H_;
    float acc = 0.f;
#pragma unroll 8
    for (int h = 0; h < H_; ++h) acc += hrow[h] * wrow[h];
    h1[b * H_ + t] = acc;
  }
}

// ---------------------------------------------------------------------------
// scores: weight-stationary MFMA, 512 thr = 8 waves, wave w owns j0 {2w,2w+1}
// (B-frags in regs). enc staged fp32->bf16 into double-buffered LDS via
// cvt_pk; ONE barrier per tile; cross-wave j-reduction DEFERRED: each wave
// writes its private plds[w][t*32+row] strip, single combine after the loop.
// ---------------------------------------------------------------------------
__global__ __launch_bounds__(512, 4) void scores_kernel(
    const float* __restrict__ enc, const short* __restrict__ W2f,
    const float* __restrict__ h1, const float* __restrict__ V,
    float* __restrict__ scores) {
  __shared__ __align__(16) short albuf[2][TILE_R * LROW];  // 2 x 16.5 KiB
  __shared__ float plds[8][TILE_R * T_PER_BLK];            // 8 KiB

  const int tid = threadIdx.x;
  const int w = tid >> 6;
  const int l = tid & 63;
  const int lo = l & 15;
  const int hi = l >> 4;
  const int bid = blockIdx.x;
  const int b = bid >> 5;  // 32 blocks per batch row
  const int s_base = (bid & 31) * (TILE_R * T_PER_BLK);

  // --- one-time: B fragments into registers (j0 = 2w, 2w+1) ---
  const bf16x8* bbase = (const bf16x8*)W2f;
  bf16x8 bfrag[8][2];
#pragma unroll
  for (int ks = 0; ks < 8; ++ks)
#pragma unroll
    for (int jj = 0; jj < 2; ++jj)
      bfrag[ks][jj] = bbase[(ks * 16 + (2 * w + jj)) * 64 + l];

  float h1v[2], Vv[2];
#pragma unroll
  for (int jj = 0; jj < 2; ++jj) {
    h1v[jj] = h1[b * H_ + (2 * w + jj) * 16 + lo];
    Vv[jj] = V[(2 * w + jj) * 16 + lo];
  }

  // staging geometry: thread covers rows r0, r0+16 at col chunk kc0*8
  const int r0 = tid >> 5;   // 0..15
  const int kc0 = tid & 31;  // 8-float col chunk
  const float4* gsrc = (const float4*)(enc + (size_t)b * S_ * H_);

  // prologue: stage tile 0
  {
    size_t gi0 = ((size_t)(s_base + r0) * (H_ / 4)) + kc0 * 2;
    size_t gi1 = ((size_t)(s_base + r0 + 16) * (H_ / 4)) + kc0 * 2;
    float4 a0 = gsrc[gi0], a1 = gsrc[gi0 + 1];
    float4 b0 = gsrc[gi1], b1 = gsrc[gi1 + 1];
    *(bf16x8*)&albuf[0][r0 * LROW + kc0 * 8] = pack8(a0, a1);
    *(bf16x8*)&albuf[0][(r0 + 16) * LROW + kc0 * 8] = pack8(b0, b1);
  }
  __syncthreads();

  for (int t = 0; t < T_PER_BLK; ++t) {
    const int cur = t & 1;

    // issue next tile's global loads (complete under the MFMAs/epilogue)
    float4 na0, na1, nb0, nb1;
    if (t + 1 < T_PER_BLK) {
      size_t gi0 =
          ((size_t)(s_base + (t + 1) * TILE_R + r0) * (H_ / 4)) + kc0 * 2;
      size_t gi1 =
          ((size_t)(s_base + (t + 1) * TILE_R + r0 + 16) * (H_ / 4)) + kc0 * 2;
      na0 = gsrc[gi0];
      na1 = gsrc[gi0 + 1];
      nb0 = gsrc[gi1];
      nb1 = gsrc[gi1 + 1];
    }

    // --- MFMA phase: A from LDS, B from regs ---
    f32x4 acc[2][2];
#pragma unroll
    for (int m = 0; m < 2; ++m)
#pragma unroll
      for (int jj = 0; jj < 2; ++jj) acc[m][jj] = (f32x4){0.f, 0.f, 0.f, 0.f};

    const short* abase = &albuf[cur][lo * LROW + hi * 8];
#pragma unroll
    for (int ks = 0; ks < 8; ++ks) {
      bf16x8 a0 = *(const bf16x8*)(abase + ks * 32);
      bf16x8 a1 = *(const bf16x8*)(abase + 16 * LROW + ks * 32);
      acc[0][0] = __builtin_amdgcn_mfma_f32_16x16x32_bf16(a0, bfrag[ks][0], acc[0][0], 0, 0, 0);
      acc[0][1] = __builtin_amdgcn_mfma_f32_16x16x32_bf16(a0, bfrag[ks][1], acc[0][1], 0, 0, 0);
      acc[1][0] = __builtin_amdgcn_mfma_f32_16x16x32_bf16(a1, bfrag[ks][0], acc[1][0], 0, 0, 0);
      acc[1][1] = __builtin_amdgcn_mfma_f32_16x16x32_bf16(a1, bfrag[ks][1], acc[1][1], 0, 0, 0);
    }

    // --- epilogue: tanh + V-dot, 16-lane reduce, stash in PRIVATE strip ---
#pragma unroll
    for (int m = 0; m < 2; ++m)
#pragma unroll
      for (int r = 0; r < 4; ++r) {
        float p = fast_tanh(acc[m][0][r] + h1v[0]) * Vv[0] +
                  fast_tanh(acc[m][1][r] + h1v[1]) * Vv[1];
        p += __shfl_xor(p, 1, 16);
        p += __shfl_xor(p, 2, 16);
        p += __shfl_xor(p, 4, 16);
        p += __shfl_xor(p, 8, 16);
        if (lo == 0) plds[w][t * TILE_R + m * 16 + hi * 4 + r] = p;
      }

    // stage next tile into the other buffer (safe: barrier at end of t-1
    // guarantees all waves finished reading it)
    if (t + 1 < T_PER_BLK) {
      *(bf16x8*)&albuf[cur ^ 1][r0 * LROW + kc0 * 8] = pack8(na0, na1);
      *(bf16x8*)&albuf[cur ^ 1][(r0 + 16) * LROW + kc0 * 8] = pack8(nb0, nb1);
    }
    __syncthreads();
  }

  // single cross-wave combine for all 256 rows
  if (tid < TILE_R * T_PER_BLK) {
    float s = 0.f;
#pragma unroll
    for (int ww = 0; ww < 8; ++ww) s += plds[ww][tid];
    scores[(size_t)b * S_ + s_base + tid] = s;
  }
}

// ---------------------------------------------------------------------------
// softmax over S per batch row. grid=B, block=1024, 8 values/thread in regs.
// ---------------------------------------------------------------------------
__global__ __launch_bounds__(1024) void softmax_kernel(
    const float* __restrict__ scores, float* __restrict__ attn) {
  __shared__ float redm[17];
  __shared__ float reds[17];
  const int b = blockIdx.x;
  const int tid = threadIdx.x;
  const int wave = tid >> 6;
  const int lane = tid & 63;

  const float4* sp = (const float4*)(scores + b * S_);
  float4 v0 = sp[tid * 2];
  float4 v1 = sp[tid * 2 + 1];
  float x[8] = {v0.x, v0.y, v0.z, v0.w, v1.x, v1.y, v1.z, v1.w};

  float m = x[0];
#pragma unroll
  for (int j = 1; j < 8; ++j) m = fmaxf(m, x[j]);
#pragma unroll
  for (int off = 32; off > 0; off >>= 1) m = fmaxf(m, __shfl_xor(m, off, 64));
  if (lane == 0) redm[wave] = m;
  __syncthreads();
  if (tid == 0) {
    float mm = redm[0];
    for (int i = 1; i < 16; ++i) mm = fmaxf(mm, redm[i]);
    redm[16] = mm;
  }
  __syncthreads();
  m = redm[16];

  float e[8];
  float s = 0.f;
#pragma unroll
  for (int j = 0; j < 8; ++j) {
    e[j] = expf(x[j] - m);
    s += e[j];
  }
#pragma unroll
  for (int off = 32; off > 0; off >>= 1) s += __shfl_xor(s, off, 64);
  if (lane == 0) reds[wave] = s;
  __syncthreads();
  if (tid == 0) {
    float ss = 0.f;
    for (int i = 0; i < 16; ++i) ss += reds[i];
    reds[16] = ss;
  }
  __syncthreads();
  const float inv = 1.f / reds[16];

  float4 o0 = {e[0] * inv, e[1] * inv, e[2] * inv, e[3] * inv};
  float4 o1 = {e[4] * inv, e[5] * inv, e[6] * inv, e[7] * inv};
  float4* op = (float4*)(attn + b * S_);
  op[tid * 2] = o0;
  op[tid * 2 + 1] = o1;
}

// ---------------------------------------------------------------------------
// context partial sums: block (chunk, b), thread = h. 32 s-rows per chunk.
// ---------------------------------------------------------------------------
__global__ __launch_bounds__(256) void ctx_partial_kernel(
    const float* __restrict__ enc, const float* __restrict__ attn,
    float* __restrict__ partial) {
  const int chunk = blockIdx.x;
  const int b = blockIdx.y;
  const int h = threadIdx.x;
  const int sbase = chunk * CHUNK_S;
  const float* ap = attn + b * S_ + sbase;
  const float* ep = enc + ((size_t)(b * S_ + sbase)) * H_ + h;
  float acc = 0.f;
#pragma unroll 8
  for (int s = 0; s < CHUNK_S; ++s) acc += ap[s] * ep[(size_t)s * H_];
  partial[(b * NCHUNK + chunk) * H_ + h] = acc;
}

// ---------------------------------------------------------------------------
// fused reduce + tile: block (h, b): reduce 256 partials -> ctx, write
// out0[b][h][0..S) broadcast + out1[b][h].
// ---------------------------------------------------------------------------
__global__ __launch_bounds__(256) void ctx_tile_kernel(
    const float* __restrict__ partial, float* __restrict__ out0,
    float* __restrict__ out1) {
  __shared__ float red[4];
  const int h = blockIdx.x;
  const int b = blockIdx.y;
  const int tid = threadIdx.x;
  const int wave = tid >> 6;
  const int lane = tid & 63;

  float v = partial[(b * NCHUNK + tid) * H_ + h];
#pragma unroll
  for (int off = 32; off > 0; off >>= 1) v += __shfl_xor(v, off, 64);
  if (lane == 0) red[wave] = v;
  __syncthreads();
  if (tid == 0) red[0] = red[0] + red[1] + red[2] + red[3];
  __syncthreads();
  const float ctx = red[0];

  if (tid == 0) out1[b * H_ + h] = ctx;
  float4 vv = {ctx, ctx, ctx, ctx};
  float4* op = (float4*)(out0 + ((size_t)b * H_ + h) * S_);
#pragma unroll 4
  for (int i = tid; i < S_ / 4; i += 256) op[i] = vv;
}

extern "C" void kernel_launch(void* const* d_in, const int* in_sizes, int n_in,
                              void* d_out, int out_size, void* d_ws,
                              size_t ws_size, hipStream_t stream) {
  const float* hidden = (const float*)d_in[0];
  const float* enc = (const float*)d_in[1];
  const float* W1 = (const float*)d_in[2];
  const float* W2 = (const float*)d_in[3];
  const float* V = (const float*)d_in[4];

  float* out0 = (float*)d_out;                // [B,H,S] context tiled
  float* out1 = out0 + (size_t)B_ * H_ * S_;  // [B,H]   context
  float* out2 = out1 + B_ * H_;               // [B,S]   attn

  float* ws = (float*)d_ws;
  short* W2f = (short*)ws;                    // 65536 shorts = 32768 float slots
  float* h1 = ws + 32768;                     // 4096
  float* scores = h1 + B_ * H_;               // 131072
  float* partial = scores + (size_t)B_ * S_;  // B*NCHUNK*H = 1048576

  prep_kernel<<<48, 256, 0, stream>>>(hidden, W1, W2, W2f, h1);
  scores_kernel<<<B_ * S_ / (TILE_R * T_PER_BLK), 512, 0, stream>>>(
      enc, W2f, h1, V, scores);
  softmax_kernel<<<B_, 1024, 0, stream>>>(scores, out2);
  ctx_partial_kernel<<<dim3(NCHUNK, B_), 256, 0, stream>>>(enc, out2, partial);
  ctx_tile_kernel<<<dim3(H_, B_), 256, 0, stream>>>(partial, out0, out1);
}

// Round 5
// 78.635 us; speedup vs baseline: 3.8721x; 1.2482x over previous
//
#include <hip/hip_runtime.h>
#include <hip/hip_bf16.h>
#include <math.h>

#define B_ 16
#define S_ 8192
#define H_ 256
#define NBLK 32      // scores blocks per batch row
#define TILE_R 32    // s-rows per tile
#define T_PER_BLK 8  // tiles per block -> block covers 256 rows
#define LROW 264     // shorts per LDS row: 256 + 8 pad (132 dwords)

using bf16x8 = __attribute__((ext_vector_type(8))) short;
using f32x4 = __attribute__((ext_vector_type(4))) float;

// fp32 -> bf16 RNE (scalar, for prep one-time packing)
__device__ inline short f2bf(float x) {
  union {
    float f;
    unsigned u;
  } v;
  v.f = x;
  unsigned r = v.u + 0x7FFFu + ((v.u >> 16) & 1u);
  return (short)(r >> 16);
}

// pack 8 fp32 -> 8 bf16 via v_cvt_pk_bf16_f32
__device__ inline bf16x8 pack8(float4 a, float4 b) {
  union {
    __hip_bfloat162 h[4];
    bf16x8 v;
  } u;
  u.h[0] = __float22bfloat162_rn(make_float2(a.x, a.y));
  u.h[1] = __float22bfloat162_rn(make_float2(a.z, a.w));
  u.h[2] = __float22bfloat162_rn(make_float2(b.x, b.y));
  u.h[3] = __float22bfloat162_rn(make_float2(b.z, b.w));
  return u.v;
}

// tanh(x) = 1 - 2/(exp2(2x*log2e)+1)
__device__ inline float fast_tanh(float x) {
  float e = exp2f(x * 2.885390082f);
  return fmaf(-2.f, __builtin_amdgcn_rcpf(e + 1.f), 1.f);
}

// ---------------------------------------------------------------------------
// prep: blocks 0..31 pack W2 into MFMA B-fragment-major bf16; blocks 32..47:
// h1[b][k] = sum_h hidden[b][h]*W1[k][h]
// ---------------------------------------------------------------------------
__global__ __launch_bounds__(256) void prep_kernel(
    const float* __restrict__ hidden, const float* __restrict__ W1,
    const float* __restrict__ W2, short* __restrict__ W2f,
    float* __restrict__ h1) {
  const int blk = blockIdx.x;
  const int t = threadIdx.x;
  if (blk < 32) {
    const int gid = blk * 256 + t;  // 0..8191
    const int l = gid & 63;
    const int j0 = (gid >> 6) & 15;
    const int ks = gid >> 10;  // 0..7
    const int row = j0 * 16 + (l & 15);
    const int col = ks * 32 + (l >> 4) * 8;
    const float* wp = W2 + row * H_ + col;
    bf16x8 out;
#pragma unroll
    for (int i = 0; i < 8; ++i) out[i] = f2bf(wp[i]);
    *(bf16x8*)(W2f + (size_t)gid * 8) = out;
  } else {
    const int b = blk - 32;
    const float* hrow = hidden + b * H_;
    const float* wrow = W1 + t * H_;
    float acc = 0.f;
#pragma unroll 8
    for (int h = 0; h < H_; ++h) acc += hrow[h] * wrow[h];
    h1[b * H_ + t] = acc;
  }
}

// ---------------------------------------------------------------------------
// scores_ctx: fused GEMM + tanh/V-dot + UNNORMALIZED softmax-context.
// 512 thr = 8 waves, weight-stationary (wave w owns j0 {2w,2w+1} in regs).
// Per tile: MFMA -> epilogue (8-shfl value-split reduce) -> cross-wave score
// combine + exp (threads 0..31) -> PV step (all threads: c[h] += e*enc_lds)
// -> stage next tile. No max subtraction needed: |score| <= ||V||_1 <= 16.
// Outputs: expsc[b][s], c_blk[b][blk][h], l_blk[b][blk].
// ---------------------------------------------------------------------------
__global__ __launch_bounds__(512, 4) void scores_ctx_kernel(
    const float* __restrict__ enc, const short* __restrict__ W2f,
    const float* __restrict__ h1, const float* __restrict__ V,
    float* __restrict__ expsc, float* __restrict__ c_blk,
    float* __restrict__ l_blk) {
  __shared__ __align__(16) short albuf[2][TILE_R * LROW];  // 2 x 16.5 KiB
  __shared__ float pcomb[8][33];
  __shared__ float avec[TILE_R];
  __shared__ float2 clds2[4][129];

  const int tid = threadIdx.x;
  const int w = tid >> 6;
  const int l = tid & 63;
  const int lo = l & 15;
  const int hi = l >> 4;
  const int bid = blockIdx.x;
  const int b = bid >> 5;
  const int blk = bid & 31;
  const int s_base = blk * (TILE_R * T_PER_BLK);

  // --- one-time: B fragments into registers (j0 = 2w, 2w+1) ---
  const bf16x8* bbase = (const bf16x8*)W2f;
  bf16x8 bfrag[8][2];
#pragma unroll
  for (int ks = 0; ks < 8; ++ks)
#pragma unroll
    for (int jj = 0; jj < 2; ++jj)
      bfrag[ks][jj] = bbase[(ks * 16 + (2 * w + jj)) * 64 + l];

  float h1v[2], Vv[2];
#pragma unroll
  for (int jj = 0; jj < 2; ++jj) {
    h1v[jj] = h1[b * H_ + (2 * w + jj) * 16 + lo];
    Vv[jj] = V[(2 * w + jj) * 16 + lo];
  }

  // staging ids: thread covers rows r0, r0+16 at col chunk kc0*8
  const int r0 = tid >> 5;   // 0..15
  const int kc0 = tid & 31;  // 8-float col chunk
  const float4* gsrc = (const float4*)(enc + (size_t)b * S_ * H_);

  // PV ids: thread covers dword-col cp (h = 2cp, 2cp+1), rows rg*8..rg*8+7
  const int rg = tid >> 7;   // 0..3
  const int cp = tid & 127;  // dword column
  float c0 = 0.f, c1 = 0.f, l_part = 0.f;

  // prologue: stage tile 0
  {
    size_t gi0 = ((size_t)(s_base + r0) * (H_ / 4)) + kc0 * 2;
    size_t gi1 = ((size_t)(s_base + r0 + 16) * (H_ / 4)) + kc0 * 2;
    float4 a0 = gsrc[gi0], a1 = gsrc[gi0 + 1];
    float4 b0 = gsrc[gi1], b1 = gsrc[gi1 + 1];
    *(bf16x8*)&albuf[0][r0 * LROW + kc0 * 8] = pack8(a0, a1);
    *(bf16x8*)&albuf[0][(r0 + 16) * LROW + kc0 * 8] = pack8(b0, b1);
  }
  __syncthreads();

  const int b0s = lo & 1;
  const int b1s = (lo >> 1) & 1;
  const int b2s = (lo >> 2) & 1;

  for (int t = 0; t < T_PER_BLK; ++t) {
    const int cur = t & 1;

    // issue next tile's global loads (complete under compute)
    float4 na0, na1, nb0, nb1;
    if (t + 1 < T_PER_BLK) {
      size_t gi0 =
          ((size_t)(s_base + (t + 1) * TILE_R + r0) * (H_ / 4)) + kc0 * 2;
      size_t gi1 =
          ((size_t)(s_base + (t + 1) * TILE_R + r0 + 16) * (H_ / 4)) + kc0 * 2;
      na0 = gsrc[gi0];
      na1 = gsrc[gi0 + 1];
      nb0 = gsrc[gi1];
      nb1 = gsrc[gi1 + 1];
    }

    // --- MFMA phase: A from LDS, B from regs ---
    f32x4 acc[2][2];
#pragma unroll
    for (int m = 0; m < 2; ++m)
#pragma unroll
      for (int jj = 0; jj < 2; ++jj) acc[m][jj] = (f32x4){0.f, 0.f, 0.f, 0.f};

    const short* abase = &albuf[cur][lo * LROW + hi * 8];
#pragma unroll
    for (int ks = 0; ks < 8; ++ks) {
      bf16x8 a0 = *(const bf16x8*)(abase + ks * 32);
      bf16x8 a1 = *(const bf16x8*)(abase + 16 * LROW + ks * 32);
      acc[0][0] = __builtin_amdgcn_mfma_f32_16x16x32_bf16(a0, bfrag[ks][0], acc[0][0], 0, 0, 0);
      acc[0][1] = __builtin_amdgcn_mfma_f32_16x16x32_bf16(a0, bfrag[ks][1], acc[0][1], 0, 0, 0);
      acc[1][0] = __builtin_amdgcn_mfma_f32_16x16x32_bf16(a1, bfrag[ks][0], acc[1][0], 0, 0, 0);
      acc[1][1] = __builtin_amdgcn_mfma_f32_16x16x32_bf16(a1, bfrag[ks][1], acc[1][1], 0, 0, 0);
    }

    // --- epilogue: tanh + V-dot, 8-shfl value-split 16-lane reduce ---
    // p[j], j = m*4+r
    float p0 = fast_tanh(acc[0][0][0] + h1v[0]) * Vv[0] + fast_tanh(acc[0][1][0] + h1v[1]) * Vv[1];
    float p1 = fast_tanh(acc[0][0][1] + h1v[0]) * Vv[0] + fast_tanh(acc[0][1][1] + h1v[1]) * Vv[1];
    float p2 = fast_tanh(acc[0][0][2] + h1v[0]) * Vv[0] + fast_tanh(acc[0][1][2] + h1v[1]) * Vv[1];
    float p3 = fast_tanh(acc[0][0][3] + h1v[0]) * Vv[0] + fast_tanh(acc[0][1][3] + h1v[1]) * Vv[1];
    float p4 = fast_tanh(acc[1][0][0] + h1v[0]) * Vv[0] + fast_tanh(acc[1][1][0] + h1v[1]) * Vv[1];
    float p5 = fast_tanh(acc[1][0][1] + h1v[0]) * Vv[0] + fast_tanh(acc[1][1][1] + h1v[1]) * Vv[1];
    float p6 = fast_tanh(acc[1][0][2] + h1v[0]) * Vv[0] + fast_tanh(acc[1][1][2] + h1v[1]) * Vv[1];
    float p7 = fast_tanh(acc[1][0][3] + h1v[0]) * Vv[0] + fast_tanh(acc[1][1][3] + h1v[1]) * Vv[1];

    // stage 1 (xor 1): keep 4, own idx = 2i+b0s
    float q0 = (b0s ? p1 : p0) + __shfl_xor((b0s ? p0 : p1), 1, 16);
    float q1 = (b0s ? p3 : p2) + __shfl_xor((b0s ? p2 : p3), 1, 16);
    float q2 = (b0s ? p5 : p4) + __shfl_xor((b0s ? p4 : p5), 1, 16);
    float q3 = (b0s ? p7 : p6) + __shfl_xor((b0s ? p6 : p7), 1, 16);
    // stage 2 (xor 2): keep 2, idx = 4i+2b1+b0
    float r0q = (b1s ? q1 : q0) + __shfl_xor((b1s ? q0 : q1), 2, 16);
    float r1q = (b1s ? q3 : q2) + __shfl_xor((b1s ? q2 : q3), 2, 16);
    // stage 3 (xor 4): keep 1, idx = lo&7
    float u = (b2s ? r1q : r0q) + __shfl_xor((b2s ? r0q : r1q), 4, 16);
    // stage 4 (xor 8): full 16-lane sum
    u += __shfl_xor(u, 8, 16);

    if (lo < 8) {
      const int row = ((lo >> 2) & 1) * 16 + hi * 4 + (lo & 3);
      pcomb[w][row] = u;
    }
    __syncthreads();  // B1: pcomb ready

    if (tid < TILE_R) {
      float s = 0.f;
#pragma unroll
      for (int ww = 0; ww < 8; ++ww) s += pcomb[ww][tid];
      float e = exp2f(s * 1.44269504f);
      avec[tid] = e;
      expsc[(size_t)b * S_ + s_base + t * TILE_R + tid] = e;
      l_part += e;
    }
    __syncthreads();  // B2: avec ready

    // --- PV: c[h] += exp(s) * enc_bf16[s][h], enc tile still in LDS ---
    const unsigned* ab32 = (const unsigned*)&albuf[cur][0];
#pragma unroll
    for (int k = 0; k < 8; ++k) {
      const int r = rg * 8 + k;
      unsigned vb = ab32[r * 132 + cp];
      float a = avec[r];
      float he = __uint_as_float(vb << 16);
      float ho = __uint_as_float(vb & 0xFFFF0000u);
      c0 = fmaf(a, he, c0);
      c1 = fmaf(a, ho, c1);
    }

    // stage next tile into the other buffer
    if (t + 1 < T_PER_BLK) {
      *(bf16x8*)&albuf[cur ^ 1][r0 * LROW + kc0 * 8] = pack8(na0, na1);
      *(bf16x8*)&albuf[cur ^ 1][(r0 + 16) * LROW + kc0 * 8] = pack8(nb0, nb1);
    }
    __syncthreads();  // B3: next tile staged / albuf[cur] free
  }

  // final combines
  clds2[rg][cp] = make_float2(c0, c1);
  __syncthreads();
  if (tid < 128) {
    float2 s0 = clds2[0][tid], s1 = clds2[1][tid];
    float2 s2 = clds2[2][tid], s3 = clds2[3][tid];
    float2 r;
    r.x = s0.x + s1.x + s2.x + s3.x;
    r.y = s0.y + s1.y + s2.y + s3.y;
    ((float2*)(c_blk + ((size_t)(b * NBLK + blk)) * H_))[tid] = r;
  }
  if (w == 0) {
    float lp = l_part;  // nonzero only in lanes 0..31
#pragma unroll
    for (int off = 32; off > 0; off >>= 1) lp += __shfl_xor(lp, off, 64);
    if (l == 0) l_blk[b * NBLK + blk] = lp;
  }
}

// ---------------------------------------------------------------------------
// attn_norm: out2[b][s] = expsc[b][s] / sum(l_blk[b][*]). grid (4, B), 256thr.
// ---------------------------------------------------------------------------
__global__ __launch_bounds__(256) void attn_norm_kernel(
    const float* __restrict__ expsc, const float* __restrict__ l_blk,
    float* __restrict__ out2) {
  const int b = blockIdx.y;
  const int tid = threadIdx.x;
  float lg = 0.f;
#pragma unroll
  for (int j = 0; j < NBLK; ++j) lg += l_blk[b * NBLK + j];
  const float inv = 1.f / lg;
  const size_t base = (size_t)b * S_ + blockIdx.x * 2048;
  const float4* ip = (const float4*)(expsc + base);
  float4* op = (float4*)(out2 + base);
  float4 x0 = ip[tid * 2];
  float4 x1 = ip[tid * 2 + 1];
  float4 y0 = {x0.x * inv, x0.y * inv, x0.z * inv, x0.w * inv};
  float4 y1 = {x1.x * inv, x1.y * inv, x1.z * inv, x1.w * inv};
  op[tid * 2] = y0;
  op[tid * 2 + 1] = y1;
}

// ---------------------------------------------------------------------------
// ctx_tile: block (h,b): ctx = sum_blk c_blk / lg; write out1 + out0 row.
// ---------------------------------------------------------------------------
__global__ __launch_bounds__(256) void ctx_tile_kernel(
    const float* __restrict__ c_blk, const float* __restrict__ l_blk,
    float* __restrict__ out0, float* __restrict__ out1) {
  const int h = blockIdx.x;
  const int b = blockIdx.y;
  const int tid = threadIdx.x;
  float lg = 0.f;
#pragma unroll
  for (int j = 0; j < NBLK; ++j) lg += l_blk[b * NBLK + j];
  float cs = 0.f;
#pragma unroll
  for (int j = 0; j < NBLK; ++j)
    cs += c_blk[((size_t)(b * NBLK + j)) * H_ + h];
  const float ctx = cs / lg;
  if (tid == 0) out1[b * H_ + h] = ctx;
  float4 vv = {ctx, ctx, ctx, ctx};
  float4* op = (float4*)(out0 + ((size_t)b * H_ + h) * S_);
#pragma unroll 4
  for (int i = tid; i < S_ / 4; i += 256) op[i] = vv;
}

extern "C" void kernel_launch(void* const* d_in, const int* in_sizes, int n_in,
                              void* d_out, int out_size, void* d_ws,
                              size_t ws_size, hipStream_t stream) {
  const float* hidden = (const float*)d_in[0];
  const float* enc = (const float*)d_in[1];
  const float* W1 = (const float*)d_in[2];
  const float* W2 = (const float*)d_in[3];
  const float* V = (const float*)d_in[4];

  float* out0 = (float*)d_out;                // [B,H,S] context tiled
  float* out1 = out0 + (size_t)B_ * H_ * S_;  // [B,H]   context
  float* out2 = out1 + B_ * H_;               // [B,S]   attn

  float* ws = (float*)d_ws;
  short* W2f = (short*)ws;                     // 65536 shorts = 32768 floats
  float* h1 = ws + 32768;                      // 4096
  float* expsc = h1 + B_ * H_;                 // B*S = 131072
  float* l_blk = expsc + (size_t)B_ * S_;      // 512
  float* c_blk = l_blk + B_ * NBLK;            // B*NBLK*H = 131072

  prep_kernel<<<48, 256, 0, stream>>>(hidden, W1, W2, W2f, h1);
  scores_ctx_kernel<<<B_ * NBLK, 512, 0, stream>>>(enc, W2f, h1, V, expsc,
                                                   c_blk, l_blk);
  attn_norm_kernel<<<dim3(4, B_), 256, 0, stream>>>(expsc, l_blk, out2);
  ctx_tile_kernel<<<dim3(H_, B_), 256, 0, stream>>>(c_blk, l_blk, out0, out1);
}

// Round 6
// 76.672 us; speedup vs baseline: 3.9713x; 1.0256x over previous
//
#include <hip/hip_runtime.h>
#include <hip/hip_bf16.h>
#include <math.h>

#define B_ 16
#define S_ 8192
#define H_ 256
#define NBLK 32      // scores blocks per batch row
#define TILE_R 32    // s-rows per tile
#define T_PER_BLK 8  // tiles per block -> block covers 256 rows
#define LROW 264     // shorts per LDS row: 256 + 8 pad (132 dwords, 33 slots)

using bf16x8 = __attribute__((ext_vector_type(8))) short;
using f32x4 = __attribute__((ext_vector_type(4))) float;

// fp32 -> bf16 RNE (scalar, for prep one-time packing)
__device__ inline short f2bf(float x) {
  union {
    float f;
    unsigned u;
  } v;
  v.f = x;
  unsigned r = v.u + 0x7FFFu + ((v.u >> 16) & 1u);
  return (short)(r >> 16);
}

// pack 8 fp32 -> 8 bf16 via v_cvt_pk_bf16_f32
__device__ inline bf16x8 pack8(float4 a, float4 b) {
  union {
    __hip_bfloat162 h[4];
    bf16x8 v;
  } u;
  u.h[0] = __float22bfloat162_rn(make_float2(a.x, a.y));
  u.h[1] = __float22bfloat162_rn(make_float2(a.z, a.w));
  u.h[2] = __float22bfloat162_rn(make_float2(b.x, b.y));
  u.h[3] = __float22bfloat162_rn(make_float2(b.z, b.w));
  return u.v;
}

// tanh(x) = 1 - 2/(exp2(2x*log2e)+1)
__device__ inline float fast_tanh(float x) {
  float e = exp2f(x * 2.885390082f);
  return fmaf(-2.f, __builtin_amdgcn_rcpf(e + 1.f), 1.f);
}

// ---------------------------------------------------------------------------
// prep: blocks 0..31 pack W2 into MFMA B-fragment-major bf16; blocks 32..47:
// h1[b][k] = sum_h hidden[b][h]*W1[k][h]
// ---------------------------------------------------------------------------
__global__ __launch_bounds__(256) void prep_kernel(
    const float* __restrict__ hidden, const float* __restrict__ W1,
    const float* __restrict__ W2, short* __restrict__ W2f,
    float* __restrict__ h1) {
  const int blk = blockIdx.x;
  const int t = threadIdx.x;
  if (blk < 32) {
    const int gid = blk * 256 + t;  // 0..8191
    const int l = gid & 63;
    const int j0 = (gid >> 6) & 15;
    const int ks = gid >> 10;  // 0..7
    const int row = j0 * 16 + (l & 15);
    const int col = ks * 32 + (l >> 4) * 8;
    const float* wp = W2 + row * H_ + col;
    bf16x8 out;
#pragma unroll
    for (int i = 0; i < 8; ++i) out[i] = f2bf(wp[i]);
    *(bf16x8*)(W2f + (size_t)gid * 8) = out;
  } else {
    const int b = blk - 32;
    const float* hrow = hidden + b * H_;
    const float* wrow = W1 + t * H_;
    float acc = 0.f;
#pragma unroll 8
    for (int h = 0; h < H_; ++h) acc += hrow[h] * wrow[h];
    h1[b * H_ + t] = acc;
  }
}

// ---------------------------------------------------------------------------
// scores_ctx: fused GEMM + tanh/V-dot + UNNORMALIZED softmax-context.
// 512 thr = 8 waves, weight-stationary (wave w owns j0 {2w,2w+1} in regs).
// TWO barriers per tile:
//   MFMA(albuf[cur]) -> epilogue -> pcomb -> B1
//   -> [stage next tile into albuf[cur^1]  ||  8-way distributed combine:
//       wave w, lanes<4 compute avec rows 4w..4w+3] -> B2
//   -> PV from albuf[cur] (flows barrier-free into next MFMA)
// Race audit: stage(t+1) writes albuf[cur(t)] only after B1(t+1); every
// wave's PV(t) reads of albuf[cur(t)] precede its own B1(t+1). pcomb(t+1)
// writes come after B2(t); pcomb(t) reads are in [B1(t),B2(t)]. avec(t+1)
// writes come after B1(t+1) > all PV(t) reads.
// ---------------------------------------------------------------------------
__global__ __launch_bounds__(512, 4) void scores_ctx_kernel(
    const float* __restrict__ enc, const short* __restrict__ W2f,
    const float* __restrict__ h1, const float* __restrict__ V,
    float* __restrict__ expsc, float* __restrict__ c_blk,
    float* __restrict__ l_blk) {
  __shared__ __align__(16) short albuf[2][TILE_R * LROW];  // 2 x 16.5 KiB
  __shared__ float pcomb[8][33];
  __shared__ float avec[TILE_R];
  __shared__ float2 clds2[4][129];
  __shared__ float lsum[8];

  const int tid = threadIdx.x;
  const int w = tid >> 6;
  const int l = tid & 63;
  const int lo = l & 15;
  const int hi = l >> 4;
  const int bid = blockIdx.x;
  const int b = bid >> 5;
  const int blk = bid & 31;
  const int s_base = blk * (TILE_R * T_PER_BLK);

  // --- one-time: B fragments into registers (j0 = 2w, 2w+1) ---
  const bf16x8* bbase = (const bf16x8*)W2f;
  bf16x8 bfrag[8][2];
#pragma unroll
  for (int ks = 0; ks < 8; ++ks)
#pragma unroll
    for (int jj = 0; jj < 2; ++jj)
      bfrag[ks][jj] = bbase[(ks * 16 + (2 * w + jj)) * 64 + l];

  float h1v[2], Vv[2];
#pragma unroll
  for (int jj = 0; jj < 2; ++jj) {
    h1v[jj] = h1[b * H_ + (2 * w + jj) * 16 + lo];
    Vv[jj] = V[(2 * w + jj) * 16 + lo];
  }

  // staging ids: thread covers rows r0, r0+16 at col chunk kc0*8
  const int r0 = tid >> 5;   // 0..15
  const int kc0 = tid & 31;  // 8-float col chunk
  const float4* gsrc = (const float4*)(enc + (size_t)b * S_ * H_);

  // PV ids: thread covers dword-col cp (h = 2cp, 2cp+1), rows rg*8..rg*8+7
  const int rg = tid >> 7;   // 0..3
  const int cp = tid & 127;  // dword column
  float c0 = 0.f, c1 = 0.f, l_part = 0.f;

  // prologue: stage tile 0
  {
    size_t gi0 = ((size_t)(s_base + r0) * (H_ / 4)) + kc0 * 2;
    size_t gi1 = ((size_t)(s_base + r0 + 16) * (H_ / 4)) + kc0 * 2;
    float4 a0 = gsrc[gi0], a1 = gsrc[gi0 + 1];
    float4 b0 = gsrc[gi1], b1 = gsrc[gi1 + 1];
    *(bf16x8*)&albuf[0][r0 * LROW + kc0 * 8] = pack8(a0, a1);
    *(bf16x8*)&albuf[0][(r0 + 16) * LROW + kc0 * 8] = pack8(b0, b1);
  }
  __syncthreads();

  const int b0s = lo & 1;
  const int b1s = (lo >> 1) & 1;
  const int b2s = (lo >> 2) & 1;

  for (int t = 0; t < T_PER_BLK; ++t) {
    const int cur = t & 1;

    // issue next tile's global loads (complete under MFMA + epilogue)
    float4 na0, na1, nb0, nb1;
    if (t + 1 < T_PER_BLK) {
      size_t gi0 =
          ((size_t)(s_base + (t + 1) * TILE_R + r0) * (H_ / 4)) + kc0 * 2;
      size_t gi1 =
          ((size_t)(s_base + (t + 1) * TILE_R + r0 + 16) * (H_ / 4)) + kc0 * 2;
      na0 = gsrc[gi0];
      na1 = gsrc[gi0 + 1];
      nb0 = gsrc[gi1];
      nb1 = gsrc[gi1 + 1];
    }

    // --- MFMA phase: A from LDS, B from regs ---
    f32x4 acc[2][2];
#pragma unroll
    for (int m = 0; m < 2; ++m)
#pragma unroll
      for (int jj = 0; jj < 2; ++jj) acc[m][jj] = (f32x4){0.f, 0.f, 0.f, 0.f};

    const short* abase = &albuf[cur][lo * LROW + hi * 8];
#pragma unroll
    for (int ks = 0; ks < 8; ++ks) {
      bf16x8 a0 = *(const bf16x8*)(abase + ks * 32);
      bf16x8 a1 = *(const bf16x8*)(abase + 16 * LROW + ks * 32);
      acc[0][0] = __builtin_amdgcn_mfma_f32_16x16x32_bf16(a0, bfrag[ks][0], acc[0][0], 0, 0, 0);
      acc[0][1] = __builtin_amdgcn_mfma_f32_16x16x32_bf16(a0, bfrag[ks][1], acc[0][1], 0, 0, 0);
      acc[1][0] = __builtin_amdgcn_mfma_f32_16x16x32_bf16(a1, bfrag[ks][0], acc[1][0], 0, 0, 0);
      acc[1][1] = __builtin_amdgcn_mfma_f32_16x16x32_bf16(a1, bfrag[ks][1], acc[1][1], 0, 0, 0);
    }

    // --- epilogue: tanh + V-dot, 8-shfl value-split 16-lane reduce ---
    float p0 = fast_tanh(acc[0][0][0] + h1v[0]) * Vv[0] + fast_tanh(acc[0][1][0] + h1v[1]) * Vv[1];
    float p1 = fast_tanh(acc[0][0][1] + h1v[0]) * Vv[0] + fast_tanh(acc[0][1][1] + h1v[1]) * Vv[1];
    float p2 = fast_tanh(acc[0][0][2] + h1v[0]) * Vv[0] + fast_tanh(acc[0][1][2] + h1v[1]) * Vv[1];
    float p3 = fast_tanh(acc[0][0][3] + h1v[0]) * Vv[0] + fast_tanh(acc[0][1][3] + h1v[1]) * Vv[1];
    float p4 = fast_tanh(acc[1][0][0] + h1v[0]) * Vv[0] + fast_tanh(acc[1][1][0] + h1v[1]) * Vv[1];
    float p5 = fast_tanh(acc[1][0][1] + h1v[0]) * Vv[0] + fast_tanh(acc[1][1][1] + h1v[1]) * Vv[1];
    float p6 = fast_tanh(acc[1][0][2] + h1v[0]) * Vv[0] + fast_tanh(acc[1][1][2] + h1v[1]) * Vv[1];
    float p7 = fast_tanh(acc[1][0][3] + h1v[0]) * Vv[0] + fast_tanh(acc[1][1][3] + h1v[1]) * Vv[1];

    float q0 = (b0s ? p1 : p0) + __shfl_xor((b0s ? p0 : p1), 1, 16);
    float q1 = (b0s ? p3 : p2) + __shfl_xor((b0s ? p2 : p3), 1, 16);
    float q2 = (b0s ? p5 : p4) + __shfl_xor((b0s ? p4 : p5), 1, 16);
    float q3 = (b0s ? p7 : p6) + __shfl_xor((b0s ? p6 : p7), 1, 16);
    float r0q = (b1s ? q1 : q0) + __shfl_xor((b1s ? q0 : q1), 2, 16);
    float r1q = (b1s ? q3 : q2) + __shfl_xor((b1s ? q2 : q3), 2, 16);
    float u = (b2s ? r1q : r0q) + __shfl_xor((b2s ? r0q : r1q), 4, 16);
    u += __shfl_xor(u, 8, 16);

    if (lo < 8) {
      const int row = ((lo >> 2) & 1) * 16 + hi * 4 + (lo & 3);
      pcomb[w][row] = u;
    }
    __syncthreads();  // B1: pcomb ready; albuf[cur^1] readers (t-1 MFMA) done

    // stage next tile into the other buffer (overlaps the combine below)
    if (t + 1 < T_PER_BLK) {
      *(bf16x8*)&albuf[cur ^ 1][r0 * LROW + kc0 * 8] = pack8(na0, na1);
      *(bf16x8*)&albuf[cur ^ 1][(r0 + 16) * LROW + kc0 * 8] = pack8(nb0, nb1);
    }

    // distributed combine: wave w, lanes 0..3 -> rows 4w..4w+3
    if (l < 4) {
      const int row = w * 4 + l;
      float s = 0.f;
#pragma unroll
      for (int ww = 0; ww < 8; ++ww) s += pcomb[ww][row];
      float e = exp2f(s * 1.44269504f);
      avec[row] = e;
      expsc[(size_t)b * S_ + s_base + t * TILE_R + row] = e;
      l_part += e;
    }
    __syncthreads();  // B2: avec + staged buffer ready

    // --- PV: c[h] += exp(s) * enc_bf16[s][h] from albuf[cur] ---
    const unsigned* ab32 = (const unsigned*)&albuf[cur][0];
#pragma unroll
    for (int k = 0; k < 8; ++k) {
      const int r = rg * 8 + k;
      unsigned vb = ab32[r * 132 + cp];
      float a = avec[r];
      float he = __uint_as_float(vb << 16);
      float ho = __uint_as_float(vb & 0xFFFF0000u);
      c0 = fmaf(a, he, c0);
      c1 = fmaf(a, ho, c1);
    }
    // no barrier: PV(t) reads complete before this wave's B1(t+1), and
    // stage(t+1) into albuf[cur] happens only after B1(t+1).
  }

  // --- final combines ---
  float lp = l_part;  // nonzero only in lanes 0..3 of each wave
  lp += __shfl_xor(lp, 1);
  lp += __shfl_xor(lp, 2);
  if (l == 0) lsum[w] = lp;
  clds2[rg][cp] = make_float2(c0, c1);
  __syncthreads();
  if (tid < 128) {
    float2 s0 = clds2[0][tid], s1 = clds2[1][tid];
    float2 s2 = clds2[2][tid], s3 = clds2[3][tid];
    float2 r;
    r.x = s0.x + s1.x + s2.x + s3.x;
    r.y = s0.y + s1.y + s2.y + s3.y;
    ((float2*)(c_blk + ((size_t)(b * NBLK + blk)) * H_))[tid] = r;
  }
  if (tid == 0) {
    float ls = 0.f;
#pragma unroll
    for (int ww = 0; ww < 8; ++ww) ls += lsum[ww];
    l_blk[b * NBLK + blk] = ls;
  }
}

// ---------------------------------------------------------------------------
// finish: grid (260, B). bx<4: attn-norm chunk (out2 = expsc/lg);
// bx>=4: h = bx-4: ctx = sum_blk c_blk/lg -> out1 + broadcast out0 row.
// ---------------------------------------------------------------------------
__global__ __launch_bounds__(256) void finish_kernel(
    const float* __restrict__ expsc, const float* __restrict__ l_blk,
    const float* __restrict__ c_blk, float* __restrict__ out0,
    float* __restrict__ out1, float* __restrict__ out2) {
  const int bx = blockIdx.x;
  const int b = blockIdx.y;
  const int tid = threadIdx.x;
  float lg = 0.f;
#pragma unroll
  for (int j = 0; j < NBLK; ++j) lg += l_blk[b * NBLK + j];
  const float inv = 1.f / lg;

  if (bx < 4) {
    const size_t base = (size_t)b * S_ + bx * 2048;
    const float4* ip = (const float4*)(expsc + base);
    float4* op = (float4*)(out2 + base);
    float4 x0 = ip[tid * 2];
    float4 x1 = ip[tid * 2 + 1];
    float4 y0 = {x0.x * inv, x0.y * inv, x0.z * inv, x0.w * inv};
    float4 y1 = {x1.x * inv, x1.y * inv, x1.z * inv, x1.w * inv};
    op[tid * 2] = y0;
    op[tid * 2 + 1] = y1;
  } else {
    const int h = bx - 4;
    float cs = 0.f;
#pragma unroll
    for (int j = 0; j < NBLK; ++j)
      cs += c_blk[((size_t)(b * NBLK + j)) * H_ + h];
    const float ctx = cs * inv;
    if (tid == 0) out1[b * H_ + h] = ctx;
    float4 vv = {ctx, ctx, ctx, ctx};
    float4* op = (float4*)(out0 + ((size_t)b * H_ + h) * S_);
#pragma unroll 4
    for (int i = tid; i < S_ / 4; i += 256) op[i] = vv;
  }
}

extern "C" void kernel_launch(void* const* d_in, const int* in_sizes, int n_in,
                              void* d_out, int out_size, void* d_ws,
                              size_t ws_size, hipStream_t stream) {
  const float* hidden = (const float*)d_in[0];
  const float* enc = (const float*)d_in[1];
  const float* W1 = (const float*)d_in[2];
  const float* W2 = (const float*)d_in[3];
  const float* V = (const float*)d_in[4];

  float* out0 = (float*)d_out;                // [B,H,S] context tiled
  float* out1 = out0 + (size_t)B_ * H_ * S_;  // [B,H]   context
  float* out2 = out1 + B_ * H_;               // [B,S]   attn

  float* ws = (float*)d_ws;
  short* W2f = (short*)ws;                 // 65536 shorts = 32768 floats
  float* h1 = ws + 32768;                  // 4096
  float* expsc = h1 + B_ * H_;             // B*S = 131072
  float* l_blk = expsc + (size_t)B_ * S_;  // 512
  float* c_blk = l_blk + B_ * NBLK;        // B*NBLK*H = 131072

  prep_kernel<<<48, 256, 0, stream>>>(hidden, W1, W2, W2f, h1);
  scores_ctx_kernel<<<B_ * NBLK, 512, 0, stream>>>(enc, W2f, h1, V, expsc,
                                                   c_blk, l_blk);
  finish_kernel<<<dim3(H_ + 4, B_), 256, 0, stream>>>(expsc, l_blk, c_blk,
                                                      out0, out1, out2);
}